// Round 7
// baseline (274.259 us; speedup 1.0000x reference)
//
#include <hip/hip_runtime.h>
#include <hip/hip_bf16.h>
#include <hip/hip_fp16.h>

// Bahdanau location-sensitive attention, fused f16-MFMA implementation.
// R7: k_main = R6 slot pipeline + FRAGMENT REGISTER DOUBLE-BUFFER with counted
//     lgkmcnt(6): each phase issues next phase's 6 ds_reads into the alternate
//     frag buffer, waits only for the previous phase's reads, and runs 16 MFMA
//     while the new reads complete (LDS pipe overlapped under MFMA pipe).
// B=32 T=1536 H=1024 CTX=1024 CONV_OUT=32

constexpr int kB = 32, kT = 1536, kH = 1024, kC = 1024, kCO = 32;
constexpr int kM = kB * kT;      // 49152
constexpr int kKp = 1088;        // padded K: 1024 enc | 32 loc | 32 zero
constexpr int kKf = 1056;        // fallback K (1024|32)

typedef _Float16 f16;
typedef _Float16 f16x8 __attribute__((ext_vector_type(8)));
typedef float f32x4 __attribute__((ext_vector_type(4)));

// ---- primary ws layout (bytes) ----
constexpr size_t W2_A     = 0;                                   // kM*kKp f16 = 106.95 MB
constexpr size_t W2_B     = W2_A + (size_t)kM * kKp * 2;         // kC*kKp f16 = 2.23 MB
constexpr size_t W2_ADD   = W2_B + (size_t)kC * kKp * 2;         // kB*kC f32
constexpr size_t W2_SCORE = W2_ADD + (size_t)kB * kC * 4;        // 4*kM f32
constexpr size_t W2_CTXP  = W2_SCORE + (size_t)4 * kM * 4;       // 8*kB*kH f32
constexpr size_t W2_NEED  = W2_CTXP + (size_t)8 * kB * kH * 4;   // ~111.1 MB

// ---- fallback ws layout (bytes) ----
constexpr size_t WF_B     = 0;
constexpr size_t WF_LOC   = WF_B + (size_t)kC * kKf * 2;
constexpr size_t WF_ADD   = WF_LOC + (size_t)kM * kCO * 2;
constexpr size_t WF_SCORE = WF_ADD + (size_t)kB * kC * 4;
constexpr size_t WF_CTXP  = WF_SCORE + (size_t)4 * kM * 4;

__device__ __forceinline__ void gload16(const void* g, void* l) {
    __builtin_amdgcn_global_load_lds(
        (const __attribute__((address_space(1))) void*)g,
        (__attribute__((address_space(3))) void*)l, 16, 0, 0);
}

// ================================================================ primary path
__global__ void k_cvt(const float* __restrict__ enc, f16* __restrict__ Af) {
    int gid = blockIdx.x * 256 + threadIdx.x;       // < kM*kH/8
    int row = gid >> 7, c8 = gid & 127;
    const float* src = enc + (size_t)row * kH + c8 * 8;
    float4 e0 = *(const float4*)src;
    float4 e1 = *(const float4*)(src + 4);
    union { f16 h[8]; int4 q; } u;
    u.h[0] = (f16)e0.x; u.h[1] = (f16)e0.y; u.h[2] = (f16)e0.z; u.h[3] = (f16)e0.w;
    u.h[4] = (f16)e1.x; u.h[5] = (f16)e1.y; u.h[6] = (f16)e1.z; u.h[7] = (f16)e1.w;
    *(int4*)(Af + (size_t)row * kKp + c8 * 8) = u.q;
}

__global__ void k_loc(const float* __restrict__ la, const float* __restrict__ cw,
                      const float* __restrict__ cb, f16* __restrict__ Af) {
    int m = blockIdx.x * 256 + threadIdx.x;          // < kM
    int b = m / kT, t = m - b * kT;
    float x0 = (t > 0)      ? la[(size_t)b * kT + t - 1] : 0.f;
    float x1 = la[(size_t)b * kT + t];
    float x2 = (t < kT - 1) ? la[(size_t)b * kT + t + 1] : 0.f;
    union { f16 h[32]; int4 q[4]; } u;
#pragma unroll
    for (int k = 0; k < 32; ++k)
        u.h[k] = (f16)(cw[k * 3] * x0 + cw[k * 3 + 1] * x1 + cw[k * 3 + 2] * x2 + cb[k]);
    int4* dst = (int4*)(Af + (size_t)m * kKp + kH);
    dst[0] = u.q[0]; dst[1] = u.q[1]; dst[2] = u.q[2]; dst[3] = u.q[3];
    int4 z = {0, 0, 0, 0};
    dst[4] = z; dst[5] = z; dst[6] = z; dst[7] = z;   // pad cols 1056..1087
}

__global__ void k_prep_b2(const float* __restrict__ V, const float* __restrict__ U,
                          f16* __restrict__ Bf) {
    int c = blockIdx.x;
    for (int k = threadIdx.x; k < kKp; k += 256) {
        float v = (k < kH) ? V[(size_t)c * kH + k]
                : (k < kH + kCO) ? U[(size_t)c * kCO + (k - kH)] : 0.f;
        Bf[(size_t)c * kKp + k] = (f16)v;
    }
}

__global__ void k_prep_add(const float* __restrict__ dec, const float* __restrict__ W,
                           const float* __restrict__ bias, float* __restrict__ add) {
    __shared__ float dl[kH];
    int bb = blockIdx.x >> 2;
    int cc = (blockIdx.x & 3) * 256 + threadIdx.x;
    *(float4*)&dl[threadIdx.x * 4] = *(const float4*)&dec[(size_t)bb * kH + threadIdx.x * 4];
    __syncthreads();
    float acc = bias[cc];
    const float* wr = W + (size_t)cc * kH;
    for (int h = 0; h < kH; h += 4) {
        float4 wv = *(const float4*)&wr[h];
        acc += wv.x * dl[h] + wv.y * dl[h + 1] + wv.z * dl[h + 2] + wv.w * dl[h + 3];
    }
    add[(size_t)bb * kC + cc] = acc;
}

// phase helpers --------------------------------------------------
// LDS slot interior: 256 rows x 64B, phys 16B chunk = global ^ ((row&15)>>1 & 3)
#define LDA4(BUF, SB, LO) { _Pragma("unroll") for (int q = 0; q < 4; ++q)                     \
    BUF[(LO) + q] = *(const f16x8*)(smem + (SB) + aRdBase + ((LO) + q) * 1024u); }

#define LDB2(BUF, SB, NU) {                                                                   \
    BUF[0] = *(const f16x8*)(smem + (SB) + bRdBase + (NU) * 2048u);                           \
    BUF[1] = *(const f16x8*)(smem + (SB) + bRdBase + (NU) * 2048u + 1024u); }

#define MFMA16(AF, BV, NP)                                                                    \
    __builtin_amdgcn_s_setprio(1);                                                            \
    { _Pragma("unroll") for (int mi = 0; mi < 8; ++mi) {                                      \
        acc[mi][2*(NP)]   = __builtin_amdgcn_mfma_f32_16x16x32_f16(AF[mi], BV[0], acc[mi][2*(NP)],   0, 0, 0); \
        acc[mi][2*(NP)+1] = __builtin_amdgcn_mfma_f32_16x16x32_f16(AF[mi], BV[1], acc[mi][2*(NP)+1], 0, 0, 0); } } \
    __builtin_amdgcn_s_setprio(0);

// barrier, then wait ONLY for reads older than the N just-issued (counted lgkm)
#define WAITK(N)                                                                              \
    __builtin_amdgcn_s_barrier();                                                             \
    asm volatile("s_waitcnt lgkmcnt(" #N ")" ::: "memory");                                   \
    __builtin_amdgcn_sched_barrier(0);

#define STAGE_A(KT, KS, SLOT) {                                                               \
    const f16* s_ = aj0 + (KT) * 64 + (KS) * 32;                                              \
    unsigned d_ = (SLOT) * 16384u + dstA;                                                     \
    gload16(s_, smem + d_);                                                                   \
    gload16(s_ + 16 * kKp, smem + d_ + 1024u); }

#define STAGE_B(KT, KS, SLOT) {                                                               \
    const f16* s_ = bj0 + (KT) * 64 + (KS) * 32;                                              \
    unsigned d_ = 65536u + (SLOT) * 16384u + dstA;                                            \
    gload16(s_, smem + d_);                                                                   \
    gload16(s_ + 16 * kKp, smem + d_ + 1024u); }

// ---------------------------------------------------------------- fused main GEMM
// 256x256 tile, BK=64, 512 thr = 8 waves (2M x 4N), per-wave 128x64.
// LDS: A slots (2d+ks)*16384 (64KB), B slots 65536+..., add_l @131072, w_l @132096.
// Frag reg dbuf: afX/afY[8], bfv_a/bfv_b[2]; 6 ds_reads issued per phase for the
// NEXT phase; lgkmcnt(6) waits only for the previous batch -> LDS under MFMA.
__launch_bounds__(512, 2)
__global__ void k_main(const f16* __restrict__ Ag, const f16* __restrict__ Bg,
                       const float* __restrict__ add, const float* __restrict__ wvec,
                       float* __restrict__ spart) {
    __shared__ __align__(16) char smem[133120];
    float* add_l = (float*)(smem + 131072);
    float* w_l   = (float*)(smem + 132096);

    const int tid = threadIdx.x, lane = tid & 63, wave = tid >> 6;
    const int wm = wave >> 2, wn = wave & 3;
    const int raw = blockIdx.x;                       // 768 = 8 XCDs x 96
    const int swz = (raw & 7) * 96 + (raw >> 3);
    const int mt = swz >> 2, nt = swz & 3;            // nt fastest: A strip reuse in-XCD
    const int m0 = mt * 256, n0 = nt * 256;
    const int bb = m0 / kT;

    if (tid < 256) {
        add_l[tid] = add[(size_t)bb * kC + n0 + tid];
        w_l[tid]   = wvec[n0 + tid];
    }

    f32x4 acc[8][4];
#pragma unroll
    for (int i = 0; i < 8; ++i)
#pragma unroll
        for (int j = 0; j < 4; ++j) acc[i][j] = (f32x4){0.f, 0.f, 0.f, 0.f};

    // staging: each gload16 covers 16 rows x 64B; lane l -> row l>>2,
    // phys chunk l&3 <- global chunk (l&3)^((l>>3)&3).
    const int csw = (((lane & 3) ^ ((lane >> 3) & 3)) * 8);
    const f16* aj0 = Ag + (size_t)(m0 + wave * 32 + (lane >> 2)) * kKp + csw;
    const f16* bj0 = Bg + (size_t)(n0 + wave * 32 + (lane >> 2)) * kKp + csw;
    const unsigned dstA = wave * 2048u;

    // ds_read bases: row r at byte r*64, phys chunk g^((r&15)>>1 &3)
    const int g = lane >> 4, rl = lane & 15;
    const unsigned aRdBase = (unsigned)((wm * 128 + rl) * 64 + ((g ^ ((rl >> 1) & 3)) << 4));
    const unsigned bRdBase = (unsigned)((wn * 64 + rl) * 64 + ((g ^ ((rl >> 1) & 3)) << 4));

    // ---- prologue: stage slots 0,1 (tile0 ks0,ks1) + slot 2 (tile1 ks0); full drain (once)
    STAGE_A(0, 0, 0u) STAGE_B(0, 0, 0u)
    STAGE_A(0, 1, 1u) STAGE_B(0, 1, 1u)
    STAGE_A(1, 0, 2u) STAGE_B(1, 0, 2u)
    asm volatile("s_waitcnt vmcnt(0) lgkmcnt(0)" ::: "memory");
    __builtin_amdgcn_s_barrier();

    f16x8 afX[8], afY[8], bfv_a[2], bfv_b[2];
    // preload: afX <- A slot0, bfv_a <- B slot0 nu0 (10 reads; drained at first WAITK)
    LDA4(afX, 0u, 0) LDA4(afX, 0u, 4)
    LDB2(bfv_a, 65536u, 0)

    for (int t = 0; t < 17; ++t) {
        const unsigned d = (unsigned)(t & 1);
        const unsigned aC0 = d * 32768u;              // A slot ks0(t)
        const unsigned aC1 = aC0 + 16384u;            // A slot ks1(t)
        const unsigned aN0 = 32768u - aC0;            // A slot ks0(t+1)
        const unsigned bC0 = 65536u + aC0, bC1 = 65536u + aC1, bN0 = 65536u + aN0;
        const unsigned sN1 = 3u - 2u * d;             // restage slot: ks1(t+1)
        const unsigned sN0 = 2u * d;                  // restage slot: ks0(t+2)
        const int kt1 = (t + 1 < 16) ? t + 1 : 16;    // clamped: garbage never consumed
        const int kt2 = (t + 2 < 16) ? t + 2 : 16;

        // ===== P0: MFMA(afX, bfv_a -> nu0); prefetch bfv_b(ks0,nu1)+afY[0..3](ks1)
        STAGE_A(kt1, 1, sN1)
        LDB2(bfv_b, bC0, 1)
        LDA4(afY, aC1, 0)
        WAITK(6)
        MFMA16(afX, bfv_a, 0)
        __builtin_amdgcn_s_barrier();

        // ===== P1: MFMA(afX, bfv_b -> nu1); prefetch afY[4..7]+bfv_a(ks1,nu0); vmcnt(8)
        STAGE_B(kt1, 1, sN1)
        LDA4(afY, aC1, 4)
        LDB2(bfv_a, bC1, 0)
        WAITK(6)
        MFMA16(afX, bfv_b, 1)
        asm volatile("s_waitcnt vmcnt(8)" ::: "memory");
        __builtin_amdgcn_s_barrier();

        // ===== P2: MFMA(afY, bfv_a -> nu0); prefetch bfv_b(ks1,nu1)+afX[0..3](ks0,t+1)
        STAGE_A(kt2, 0, sN0)
        LDB2(bfv_b, bC1, 1)
        LDA4(afX, aN0, 0)
        WAITK(6)
        MFMA16(afY, bfv_a, 0)
        __builtin_amdgcn_s_barrier();

        // ===== P3: MFMA(afY, bfv_b -> nu1); prefetch afX[4..7]+bfv_a(ks0 t+1,nu0); vmcnt(8)
        STAGE_B(kt2, 0, sN0)
        LDA4(afX, aN0, 4)
        LDB2(bfv_a, bN0, 0)
        WAITK(6)
        MFMA16(afY, bfv_b, 1)
        asm volatile("s_waitcnt vmcnt(8)" ::: "memory");
        __builtin_amdgcn_s_barrier();
    }

    // drain in-flight garbage stages before aliasing LDS
    asm volatile("s_waitcnt vmcnt(0) lgkmcnt(0)" ::: "memory");
    __builtin_amdgcn_s_barrier();

    // ---- epilogue: e = tanh(acc + add[c]); partial score = sum_c e*w[c]
    float (*sred)[128][4] = (float (*)[128][4])(smem + 65536);
    {
        const int gq = lane >> 4;
#pragma unroll
        for (int mi = 0; mi < 8; ++mi) {
#pragma unroll
            for (int i = 0; i < 4; ++i) {
                float p = 0.f;
#pragma unroll
                for (int ni = 0; ni < 4; ++ni) {
                    int cl = wn * 64 + ni * 16 + rl;
                    float e = tanhf(acc[mi][ni][i] + add_l[cl]);
                    p += e * w_l[cl];
                }
                p += __shfl_xor(p, 1);
                p += __shfl_xor(p, 2);
                p += __shfl_xor(p, 4);
                p += __shfl_xor(p, 8);
                if (rl == 0) sred[wm][mi * 16 + gq * 4 + i][wn] = p;
            }
        }
    }
    __syncthreads();
    if (tid < 256) {
        float s = sred[tid >> 7][tid & 127][0] + sred[tid >> 7][tid & 127][1]
                + sred[tid >> 7][tid & 127][2] + sred[tid >> 7][tid & 127][3];
        spart[(size_t)nt * kM + m0 + tid] = s;
    }
}

// ================================================================ fallback path (R1, proven)
__global__ void k_prep_b_fb(const float* __restrict__ V, const float* __restrict__ U,
                            f16* __restrict__ Bf) {
    int idx = blockIdx.x * 256 + threadIdx.x;
    int c = idx / kKf, k = idx - c * kKf;
    float v = (k < kH) ? V[(size_t)c * kH + k] : U[(size_t)c * kCO + (k - kH)];
    Bf[idx] = (f16)v;
}

__global__ void k_loc_fb(const float* __restrict__ la, const float* __restrict__ cw,
                         const float* __restrict__ cb, f16* __restrict__ loc) {
    int m = blockIdx.x * 256 + threadIdx.x;
    int b = m / kT, t = m - b * kT;
    float x0 = (t > 0)      ? la[(size_t)b * kT + t - 1] : 0.f;
    float x1 = la[(size_t)b * kT + t];
    float x2 = (t < kT - 1) ? la[(size_t)b * kT + t + 1] : 0.f;
    union { f16 h[32]; int4 q[4]; } u;
#pragma unroll
    for (int k = 0; k < 32; ++k)
        u.h[k] = (f16)(cw[k * 3] * x0 + cw[k * 3 + 1] * x1 + cw[k * 3 + 2] * x2 + cb[k]);
    int4* dst = (int4*)(loc + (size_t)m * 32);
    dst[0] = u.q[0]; dst[1] = u.q[1]; dst[2] = u.q[2]; dst[3] = u.q[3];
}

__launch_bounds__(512)
__global__ void k_main_fb(const float* __restrict__ enc, const f16* __restrict__ Bf,
                          const f16* __restrict__ loc, const float* __restrict__ add,
                          const float* __restrict__ wvec, float* __restrict__ spart) {
    __shared__ __align__(16) f16 As[128 * 64];
    __shared__ __align__(16) f16 Bs[256 * 64];
    __shared__ float add_l[256], w_l[256];
    __shared__ float sred[2][64][4];

    const int tid = threadIdx.x, lane = tid & 63, wave = tid >> 6;
    const int wm = wave >> 2, wn = wave & 3;
    const int mt = blockIdx.x >> 2, nt = blockIdx.x & 3;
    const int m0 = mt * 128, n0 = nt * 256;
    const int bb = m0 / kT;

    if (tid < 256) {
        add_l[tid] = add[(size_t)bb * kC + n0 + tid];
        w_l[tid]   = wvec[n0 + tid];
    }

    f32x4 acc[4][4];
#pragma unroll
    for (int i = 0; i < 4; ++i)
#pragma unroll
        for (int j = 0; j < 4; ++j) acc[i][j] = (f32x4){0.f, 0.f, 0.f, 0.f};

    const int ar = tid >> 2, aq = tid & 3;
    const int br = tid >> 1, bh = tid & 1;
    const float* ap = enc + (size_t)(m0 + ar) * kH + aq * 16;
    const f16*   bp = Bf + (size_t)(n0 + br) * kKf;
    char* aw = (char*)As + ar * 128;
    char* bw = (char*)Bs + br * 128;
    const int axm = ar & 7, bxm = br & 7;

    for (int step = 0; step < 17; ++step) {
        if (step < 16) {
            const int k0 = step * 64;
            float4 f0 = *(const float4*)(ap + k0);
            float4 f1 = *(const float4*)(ap + k0 + 4);
            float4 f2 = *(const float4*)(ap + k0 + 8);
            float4 f3 = *(const float4*)(ap + k0 + 12);
            union { f16 h[16]; int4 q[2]; } pk;
            pk.h[0] = (f16)f0.x;  pk.h[1] = (f16)f0.y;  pk.h[2] = (f16)f0.z;  pk.h[3] = (f16)f0.w;
            pk.h[4] = (f16)f1.x;  pk.h[5] = (f16)f1.y;  pk.h[6] = (f16)f1.z;  pk.h[7] = (f16)f1.w;
            pk.h[8] = (f16)f2.x;  pk.h[9] = (f16)f2.y;  pk.h[10] = (f16)f2.z; pk.h[11] = (f16)f2.w;
            pk.h[12] = (f16)f3.x; pk.h[13] = (f16)f3.y; pk.h[14] = (f16)f3.z; pk.h[15] = (f16)f3.w;
            *(int4*)(aw + (((aq * 2 + 0) ^ axm) * 16)) = pk.q[0];
            *(int4*)(aw + (((aq * 2 + 1) ^ axm) * 16)) = pk.q[1];
            const char* bs = (const char*)(bp + k0 + bh * 32);
#pragma unroll
            for (int j = 0; j < 4; ++j) {
                int4 v = *(const int4*)(bs + j * 16);
                *(int4*)(bw + (((bh * 4 + j) ^ bxm) * 16)) = v;
            }
        } else {
            int4 v = *(const int4*)(loc + (size_t)(m0 + ar) * 32 + aq * 8);
            *(int4*)(aw + ((aq ^ axm) * 16)) = v;
#pragma unroll
            for (int j = 0; j < 2; ++j) {
                int4 w0 = *(const int4*)(bp + kH + (bh * 2 + j) * 8);
                *(int4*)(bw + (((bh * 2 + j) ^ bxm) * 16)) = w0;
            }
        }
        __syncthreads();
        const int nkk = (step < 16) ? 2 : 1;
        for (int kk = 0; kk < nkk; ++kk) {
            f16x8 af[4], bfr[4];
            const int g = lane >> 4, rl = lane & 15;
#pragma unroll
            for (int mi = 0; mi < 4; ++mi) {
                int row = wm * 64 + mi * 16 + rl;
                af[mi] = *(const f16x8*)((const char*)As + row * 128 + (((kk * 4 + g) ^ (row & 7)) * 16));
            }
#pragma unroll
            for (int ni = 0; ni < 4; ++ni) {
                int row = wn * 64 + ni * 16 + rl;
                bfr[ni] = *(const f16x8*)((const char*)Bs + row * 128 + (((kk * 4 + g) ^ (row & 7)) * 16));
            }
#pragma unroll
            for (int mi = 0; mi < 4; ++mi)
#pragma unroll
                for (int ni = 0; ni < 4; ++ni)
                    acc[mi][ni] = __builtin_amdgcn_mfma_f32_16x16x32_f16(af[mi], bfr[ni], acc[mi][ni], 0, 0, 0);
        }
        __syncthreads();
    }

#pragma unroll
    for (int mi = 0; mi < 4; ++mi) {
#pragma unroll
        for (int i = 0; i < 4; ++i) {
            float p = 0.f;
#pragma unroll
            for (int ni = 0; ni < 4; ++ni) {
                int cl = wn * 64 + ni * 16 + (lane & 15);
                float e = tanhf(acc[mi][ni][i] + add_l[cl]);
                p += e * w_l[cl];
            }
            p += __shfl_xor(p, 1);
            p += __shfl_xor(p, 2);
            p += __shfl_xor(p, 4);
            p += __shfl_xor(p, 8);
            if ((lane & 15) == 0)
                sred[wm][mi * 16 + (lane >> 4) * 4 + i][wn] = p;
        }
    }
    __syncthreads();
    if (tid < 128) {
        int r = tid & 63, w2 = tid >> 6;
        float s = sred[w2][r][0] + sred[w2][r][1] + sred[w2][r][2] + sred[w2][r][3];
        spart[(size_t)nt * kM + m0 + tid] = s;
    }
}

// ================================================================ shared epilogue kernels
__global__ void k_softmax(const float* __restrict__ spart, float* __restrict__ out_align) {
    __shared__ float red[256];
    int b = blockIdx.x, tid = threadIdx.x;
    float v[6];
    float mx = -1e30f;
#pragma unroll
    for (int i = 0; i < 6; ++i) {
        size_t idx = (size_t)b * kT + tid + i * 256;
        float s = spart[idx] + spart[kM + idx] + spart[2 * (size_t)kM + idx] + spart[3 * (size_t)kM + idx];
        v[i] = s; mx = fmaxf(mx, s);
    }
    red[tid] = mx; __syncthreads();
    for (int o = 128; o > 0; o >>= 1) { if (tid < o) red[tid] = fmaxf(red[tid], red[tid + o]); __syncthreads(); }
    mx = red[0]; __syncthreads();
    float sum = 0.f;
#pragma unroll
    for (int i = 0; i < 6; ++i) { v[i] = expf(v[i] - mx); sum += v[i]; }
    red[tid] = sum; __syncthreads();
    for (int o = 128; o > 0; o >>= 1) { if (tid < o) red[tid] += red[tid + o]; __syncthreads(); }
    float inv = 1.f / red[0];
#pragma unroll
    for (int i = 0; i < 6; ++i)
        out_align[(size_t)b * kT + tid + i * 256] = v[i] * inv;
}

__global__ void k_ctx_part(const float* __restrict__ enc, const float* __restrict__ align,
                           float* __restrict__ cpart) {
    __shared__ float al[192];
    int ci = blockIdx.x, b = blockIdx.y, tid = threadIdx.x;
    if (tid < 192) al[tid] = align[(size_t)b * kT + ci * 192 + tid];
    __syncthreads();
    float4 acc = {0.f, 0.f, 0.f, 0.f};
    const float* ep = enc + ((size_t)b * kT + (size_t)ci * 192) * kH + tid * 4;
    for (int t = 0; t < 192; ++t) {
        float a = al[t];
        float4 e = *(const float4*)(ep + (size_t)t * kH);
        acc.x += a * e.x; acc.y += a * e.y; acc.z += a * e.z; acc.w += a * e.w;
    }
    *(float4*)&cpart[((size_t)ci * kB + b) * kH + tid * 4] = acc;
}

__global__ void k_ctx_red(const float* __restrict__ cpart, float* __restrict__ out_ctx) {
    int idx = blockIdx.x * 256 + threadIdx.x;
    float s = 0.f;
#pragma unroll
    for (int ci = 0; ci < 8; ++ci) s += cpart[(size_t)ci * kB * kH + idx];
    out_ctx[idx] = s;
}

// ---------------------------------------------------------------- launch
extern "C" void kernel_launch(void* const* d_in, const int* in_sizes, int n_in,
                              void* d_out, int out_size, void* d_ws, size_t ws_size,
                              hipStream_t stream) {
    const float* dec  = (const float*)d_in[0];
    const float* enc  = (const float*)d_in[1];
    const float* la   = (const float*)d_in[2];
    const float* W    = (const float*)d_in[3];
    const float* V    = (const float*)d_in[4];
    const float* U    = (const float*)d_in[5];
    const float* bias = (const float*)d_in[6];
    const float* wv   = (const float*)d_in[7];
    const float* cw   = (const float*)d_in[8];
    const float* cb   = (const float*)d_in[9];

    char* ws = (char*)d_ws;
    float* out_ctx   = (float*)d_out;            // (B,H)
    float* out_align = (float*)d_out + kB * kH;  // (B,T)

    if (ws_size >= W2_NEED) {
        f16* Af      = (f16*)(ws + W2_A);
        f16* Bf      = (f16*)(ws + W2_B);
        float* add   = (float*)(ws + W2_ADD);
        float* spart = (float*)(ws + W2_SCORE);
        float* cpart = (float*)(ws + W2_CTXP);

        hipLaunchKernelGGL(k_prep_b2, dim3(kC),             dim3(256), 0, stream, V, U, Bf);
        hipLaunchKernelGGL(k_loc,     dim3(kM / 256),       dim3(256), 0, stream, la, cw, cb, Af);
        hipLaunchKernelGGL(k_cvt,     dim3(kM * kH / 8 / 256), dim3(256), 0, stream, enc, Af);
        hipLaunchKernelGGL(k_prep_add, dim3(kB * 4),        dim3(256), 0, stream, dec, W, bias, add);
        hipLaunchKernelGGL(k_main,    dim3((kM / 256) * 4), dim3(512), 0, stream, Af, Bf, add, wv, spart);
        hipLaunchKernelGGL(k_softmax, dim3(kB),             dim3(256), 0, stream, spart, out_align);
        hipLaunchKernelGGL(k_ctx_part, dim3(8, kB),         dim3(256), 0, stream, enc, out_align, cpart);
        hipLaunchKernelGGL(k_ctx_red, dim3(kB * kH / 256),  dim3(256), 0, stream, cpart, out_ctx);
    } else {
        f16* Bf      = (f16*)(ws + WF_B);
        f16* loc     = (f16*)(ws + WF_LOC);
        float* add   = (float*)(ws + WF_ADD);
        float* spart = (float*)(ws + WF_SCORE);
        float* cpart = (float*)(ws + WF_CTXP);

        hipLaunchKernelGGL(k_prep_b_fb, dim3(kC * kKf / 256), dim3(256), 0, stream, V, U, Bf);
        hipLaunchKernelGGL(k_loc_fb,  dim3(kM / 256),       dim3(256), 0, stream, la, cw, cb, loc);
        hipLaunchKernelGGL(k_prep_add, dim3(kB * 4),        dim3(256), 0, stream, dec, W, bias, add);
        hipLaunchKernelGGL(k_main_fb, dim3((kM / 128) * 4), dim3(512), 0, stream, enc, Bf, loc, add, wv, spart);
        hipLaunchKernelGGL(k_softmax, dim3(kB),             dim3(256), 0, stream, spart, out_align);
        hipLaunchKernelGGL(k_ctx_part, dim3(8, kB),         dim3(256), 0, stream, enc, out_align, cpart);
        hipLaunchKernelGGL(k_ctx_red, dim3(kB * kH / 256),  dim3(256), 0, stream, cpart, out_ctx);
    }
}

// Round 8
// 221.334 us; speedup vs baseline: 1.2391x; 1.2391x over previous
//
#include <hip/hip_runtime.h>
#include <hip/hip_bf16.h>
#include <hip/hip_fp16.h>

// Bahdanau location-sensitive attention, fused f16-MFMA implementation.
// R8: kill the Af-materialization pipeline (k_cvt + strided loc + cold ctx_part
//     cost ~107 us). k_main stages enc f32 DIRECTLY via global_load_lds into a
//     single-buffered 68 KB LDS tile -> 2 blocks/CU (TLP covers stage stalls,
//     the R1 regime), converts f32->f16 on the ds_read side in the MFMA shadow.
//     Tile 128x256, 8 waves (2Mx4N), per-wave 64x64, BK=64, K=16 steps + loc tail.
// B=32 T=1536 H=1024 CTX=1024 CONV_OUT=32

constexpr int kB = 32, kT = 1536, kH = 1024, kC = 1024, kCO = 32;
constexpr int kM = kB * kT;      // 49152
constexpr int kKb = 1088;        // padded B K: 1024 V | 32 U | 32 zero

typedef _Float16 f16;
typedef _Float16 f16x8 __attribute__((ext_vector_type(8)));
typedef float f32x4 __attribute__((ext_vector_type(4)));

// ---- ws layout (bytes) ----
constexpr size_t WS_B     = 0;                                   // kC*kKb f16  (2.2 MB)
constexpr size_t WS_LOC   = WS_B + (size_t)kC * kKb * 2;         // kM*64 f16   (6.3 MB)
constexpr size_t WS_ADD   = WS_LOC + (size_t)kM * 64 * 2;        // kB*kC f32
constexpr size_t WS_SCORE = WS_ADD + (size_t)kB * kC * 4;        // 4*kM f32
constexpr size_t WS_CTXP  = WS_SCORE + (size_t)4 * kM * 4;       // 8*kB*kH f32
// total ~10.5 MB (ws proven >= 111 MB by R4-R7 primary path)

__device__ __forceinline__ void gload16(const void* g, void* l) {
    __builtin_amdgcn_global_load_lds(
        (const __attribute__((address_space(1))) void*)g,
        (__attribute__((address_space(3))) void*)l, 16, 0, 0);
}

// ---------------------------------------------------------------- B pack [kC][1088] f16
__global__ void k_prep_b2(const float* __restrict__ V, const float* __restrict__ U,
                          f16* __restrict__ Bf) {
    int c = blockIdx.x;
    for (int k = threadIdx.x; k < kKb; k += 256) {
        float v = (k < kH) ? V[(size_t)c * kH + k]
                : (k < kH + kCO) ? U[(size_t)c * kCO + (k - kH)] : 0.f;
        Bf[(size_t)c * kKb + k] = (f16)v;
    }
}

// ---------------------------------------------------------------- conv1d -> locPad [M][64] f16 (cols 0..31)
__global__ void k_loc(const float* __restrict__ la, const float* __restrict__ cw,
                      const float* __restrict__ cb, f16* __restrict__ locPad) {
    int m = blockIdx.x * 256 + threadIdx.x;          // < kM
    int b = m / kT, t = m - b * kT;
    float x0 = (t > 0)      ? la[(size_t)b * kT + t - 1] : 0.f;
    float x1 = la[(size_t)b * kT + t];
    float x2 = (t < kT - 1) ? la[(size_t)b * kT + t + 1] : 0.f;
    union { f16 h[32]; int4 q[4]; } u;
#pragma unroll
    for (int k = 0; k < 32; ++k)
        u.h[k] = (f16)(cw[k * 3] * x0 + cw[k * 3 + 1] * x1 + cw[k * 3 + 2] * x2 + cb[k]);
    int4* dst = (int4*)(locPad + (size_t)m * 64);
    dst[0] = u.q[0]; dst[1] = u.q[1]; dst[2] = u.q[2]; dst[3] = u.q[3];
    // cols 32..63 left as-is: staged to LDS but never ds_read (tail computes K=32 only)
}

// ---------------------------------------------------------------- prep add = dec@W^T + bias
__global__ void k_prep_add(const float* __restrict__ dec, const float* __restrict__ W,
                           const float* __restrict__ bias, float* __restrict__ add) {
    __shared__ float dl[kH];
    int bb = blockIdx.x >> 2;
    int cc = (blockIdx.x & 3) * 256 + threadIdx.x;
    *(float4*)&dl[threadIdx.x * 4] = *(const float4*)&dec[(size_t)bb * kH + threadIdx.x * 4];
    __syncthreads();
    float acc = bias[cc];
    const float* wr = W + (size_t)cc * kH;
    for (int h = 0; h < kH; h += 4) {
        float4 wv = *(const float4*)&wr[h];
        acc += wv.x * dl[h] + wv.y * dl[h + 1] + wv.z * dl[h + 2] + wv.w * dl[h + 3];
    }
    add[(size_t)bb * kC + cc] = acc;
}

// ---------------------------------------------------------------- fused main GEMM
// Tile 128(M) x 256(N), BK=64, 512 thr = 8 waves (2M x 4N), per-wave 64x64.
// LDS (69632 B): As f32 [128 rows][16 chunks of 16B, XOR row&15] @0 (32 KB);
//   Bs f16 [256 rows][8 chunks, XOR row&7] @32768 (32 KB); add_l @65536;
//   w_l @66560; sred @67584 (2 KB). Single-buffered: stage -> sync -> compute -> sync.
// 2 blocks/CU (launch_bounds 512,4 caps VGPR+AGPR at 128) -> cross-block TLP
// hides the per-block stage drain (the R1-winning regime).
__launch_bounds__(512, 4)
__global__ void k_main(const float* __restrict__ enc, const f16* __restrict__ Bf,
                       const f16* __restrict__ locPad, const float* __restrict__ add,
                       const float* __restrict__ wvec, float* __restrict__ spart) {
    __shared__ __align__(16) char smem[69632];
    float* add_l = (float*)(smem + 65536);
    float* w_l   = (float*)(smem + 66560);
    float (*sred)[64][4] = (float (*)[64][4])(smem + 67584);

    const int tid = threadIdx.x, lane = tid & 63, wave = tid >> 6;
    const int wm = wave >> 2, wn = wave & 3;
    // bijective XCD swizzle: 1536 blocks = 8 XCDs x 192; 4 consecutive share an A strip
    const int raw = blockIdx.x;
    const int lin = (raw & 7) * 192 + (raw >> 3);
    const int mt = lin >> 2, nt = lin & 3;
    const int m0 = mt * 128, n0 = nt * 256;
    const int bb = m0 / kT;                          // 128 | 1536

    if (tid < 256) {
        add_l[tid] = add[(size_t)bb * kC + n0 + tid];
        w_l[tid]   = wvec[n0 + tid];
    }

    f32x4 acc[4][4];
#pragma unroll
    for (int i = 0; i < 4; ++i)
#pragma unroll
        for (int j = 0; j < 4; ++j) acc[i][j] = (f32x4){0.f, 0.f, 0.f, 0.f};

    // A staging (f32): 4 gloads/wave, each 4 rows x 256B. lane: row_in = l>>4,
    // phys chunk l&15 <- global chunk (l&15)^(row&15), row&15 = j*4 + row_in.
    const int rA = lane >> 4;
    const float* aSrc[4];
#pragma unroll
    for (int j = 0; j < 4; ++j) {
        int gc = (lane & 15) ^ ((j * 4 + rA) & 15);
        aSrc[j] = enc + (size_t)(m0 + wave * 16 + j * 4 + rA) * kH + gc * 4;
    }
    // B staging (f16): 4 gloads/wave, each 8 rows x 128B. row&7 = l>>3.
    const int rB = lane >> 3;
    const int gcB = (lane & 7) ^ (rB & 7);
    const f16* bSrc[4];
#pragma unroll
    for (int j = 0; j < 4; ++j)
        bSrc[j] = Bf + (size_t)(n0 + wave * 32 + j * 8 + rB) * kKb + gcB * 8;

    const unsigned aDst = wave * 4096u;
    const unsigned bDst = 32768u + wave * 4096u;
    const int g = lane >> 4, rl = lane & 15;

    for (int t = 0; t < 16; ++t) {
        // ---- stage K-step t (A f32 32 KB + B f16 32 KB), then full drain
#pragma unroll
        for (int j = 0; j < 4; ++j) gload16(aSrc[j] + t * 64, smem + aDst + j * 1024);
#pragma unroll
        for (int j = 0; j < 4; ++j) gload16(bSrc[j] + t * 64, smem + bDst + j * 1024);
        __syncthreads();
        // ---- compute (compiler-scheduled lgkm; cvt overlaps MFMA pipe)
#pragma unroll
        for (int kk = 0; kk < 2; ++kk) {
            f16x8 bfv[4];
#pragma unroll
            for (int ni = 0; ni < 4; ++ni)
                bfv[ni] = *(const f16x8*)(smem + 32768 + (wn * 64 + ni * 16 + rl) * 128
                                          + (((kk * 4 + g) ^ (rl & 7)) << 4));
#pragma unroll
            for (int mi = 0; mi < 4; ++mi) {
                const unsigned rowByte = (unsigned)((wm * 64 + mi * 16 + rl) * 256);
                float4 lo = *(const float4*)(smem + rowByte + (((kk * 8 + 2 * g) ^ rl) << 4));
                float4 hi = *(const float4*)(smem + rowByte + (((kk * 8 + 2 * g + 1) ^ rl) << 4));
                f16x8 ah;
                ah[0] = (f16)lo.x; ah[1] = (f16)lo.y; ah[2] = (f16)lo.z; ah[3] = (f16)lo.w;
                ah[4] = (f16)hi.x; ah[5] = (f16)hi.y; ah[6] = (f16)hi.z; ah[7] = (f16)hi.w;
#pragma unroll
                for (int ni = 0; ni < 4; ++ni)
                    acc[mi][ni] = __builtin_amdgcn_mfma_f32_16x16x32_f16(ah, bfv[ni], acc[mi][ni], 0, 0, 0);
            }
        }
        __syncthreads();
    }

    // ---- tail: loc @ U^T, K=32 (A from locPad f16; B cols 1024..1087 incl zero pad)
    {
        const f16* tS0 = locPad + (size_t)(m0 + wave * 16 + 0 + rB) * 64 + gcB * 8;
        const f16* tS1 = locPad + (size_t)(m0 + wave * 16 + 8 + rB) * 64 + gcB * 8;
        gload16(tS0, smem + wave * 2048u);
        gload16(tS1, smem + wave * 2048u + 1024u);
#pragma unroll
        for (int j = 0; j < 4; ++j) gload16(bSrc[j] + 1024, smem + bDst + j * 1024);
        __syncthreads();
        f16x8 bfv[4];
#pragma unroll
        for (int ni = 0; ni < 4; ++ni)
            bfv[ni] = *(const f16x8*)(smem + 32768 + (wn * 64 + ni * 16 + rl) * 128
                                      + ((g ^ (rl & 7)) << 4));
#pragma unroll
        for (int mi = 0; mi < 4; ++mi) {
            f16x8 ah = *(const f16x8*)(smem + (wm * 64 + mi * 16 + rl) * 128
                                       + ((g ^ (rl & 7)) << 4));
#pragma unroll
            for (int ni = 0; ni < 4; ++ni)
                acc[mi][ni] = __builtin_amdgcn_mfma_f32_16x16x32_f16(ah, bfv[ni], acc[mi][ni], 0, 0, 0);
        }
        __syncthreads();
    }

    // ---- epilogue: e = tanh(acc + add[c]); partial score = sum_c e*w[c]
#pragma unroll
    for (int mi = 0; mi < 4; ++mi) {
#pragma unroll
        for (int i = 0; i < 4; ++i) {
            float p = 0.f;
#pragma unroll
            for (int ni = 0; ni < 4; ++ni) {
                int cl = wn * 64 + ni * 16 + rl;
                float e = tanhf(acc[mi][ni][i] + add_l[cl]);
                p += e * w_l[cl];
            }
            p += __shfl_xor(p, 1);
            p += __shfl_xor(p, 2);
            p += __shfl_xor(p, 4);
            p += __shfl_xor(p, 8);
            if (rl == 0) sred[wm][mi * 16 + g * 4 + i][wn] = p;
        }
    }
    __syncthreads();
    if (tid < 128) {
        int r = tid & 63, w2 = tid >> 6;
        float s = sred[w2][r][0] + sred[w2][r][1] + sred[w2][r][2] + sred[w2][r][3];
        spart[(size_t)nt * kM + m0 + tid] = s;
    }
}

// ---------------------------------------------------------------- softmax over T
__global__ void k_softmax(const float* __restrict__ spart, float* __restrict__ out_align) {
    __shared__ float red[256];
    int b = blockIdx.x, tid = threadIdx.x;
    float v[6];
    float mx = -1e30f;
#pragma unroll
    for (int i = 0; i < 6; ++i) {
        size_t idx = (size_t)b * kT + tid + i * 256;
        float s = spart[idx] + spart[kM + idx] + spart[2 * (size_t)kM + idx] + spart[3 * (size_t)kM + idx];
        v[i] = s; mx = fmaxf(mx, s);
    }
    red[tid] = mx; __syncthreads();
    for (int o = 128; o > 0; o >>= 1) { if (tid < o) red[tid] = fmaxf(red[tid], red[tid + o]); __syncthreads(); }
    mx = red[0]; __syncthreads();
    float sum = 0.f;
#pragma unroll
    for (int i = 0; i < 6; ++i) { v[i] = expf(v[i] - mx); sum += v[i]; }
    red[tid] = sum; __syncthreads();
    for (int o = 128; o > 0; o >>= 1) { if (tid < o) red[tid] += red[tid + o]; __syncthreads(); }
    float inv = 1.f / red[0];
#pragma unroll
    for (int i = 0; i < 6; ++i)
        out_align[(size_t)b * kT + tid + i * 256] = v[i] * inv;
}

// ---------------------------------------------------------------- context
__global__ void k_ctx_part(const float* __restrict__ enc, const float* __restrict__ align,
                           float* __restrict__ cpart) {
    __shared__ float al[192];
    int ci = blockIdx.x, b = blockIdx.y, tid = threadIdx.x;
    if (tid < 192) al[tid] = align[(size_t)b * kT + ci * 192 + tid];
    __syncthreads();
    float4 acc = {0.f, 0.f, 0.f, 0.f};
    const float* ep = enc + ((size_t)b * kT + (size_t)ci * 192) * kH + tid * 4;
    for (int t = 0; t < 192; ++t) {
        float a = al[t];
        float4 e = *(const float4*)(ep + (size_t)t * kH);
        acc.x += a * e.x; acc.y += a * e.y; acc.z += a * e.z; acc.w += a * e.w;
    }
    *(float4*)&cpart[((size_t)ci * kB + b) * kH + tid * 4] = acc;
}

__global__ void k_ctx_red(const float* __restrict__ cpart, float* __restrict__ out_ctx) {
    int idx = blockIdx.x * 256 + threadIdx.x;
    float s = 0.f;
#pragma unroll
    for (int ci = 0; ci < 8; ++ci) s += cpart[(size_t)ci * kB * kH + idx];
    out_ctx[idx] = s;
}

// ---------------------------------------------------------------- launch
extern "C" void kernel_launch(void* const* d_in, const int* in_sizes, int n_in,
                              void* d_out, int out_size, void* d_ws, size_t ws_size,
                              hipStream_t stream) {
    const float* dec  = (const float*)d_in[0];
    const float* enc  = (const float*)d_in[1];
    const float* la   = (const float*)d_in[2];
    const float* W    = (const float*)d_in[3];
    const float* V    = (const float*)d_in[4];
    const float* U    = (const float*)d_in[5];
    const float* bias = (const float*)d_in[6];
    const float* wv   = (const float*)d_in[7];
    const float* cw   = (const float*)d_in[8];
    const float* cb   = (const float*)d_in[9];

    char* ws = (char*)d_ws;
    f16* Bf      = (f16*)(ws + WS_B);
    f16* locPad  = (f16*)(ws + WS_LOC);
    float* add   = (float*)(ws + WS_ADD);
    float* spart = (float*)(ws + WS_SCORE);
    float* cpart = (float*)(ws + WS_CTXP);

    float* out_ctx   = (float*)d_out;            // (B,H)
    float* out_align = (float*)d_out + kB * kH;  // (B,T)

    hipLaunchKernelGGL(k_prep_b2,  dim3(kC),            dim3(256), 0, stream, V, U, Bf);
    hipLaunchKernelGGL(k_loc,      dim3(kM / 256),      dim3(256), 0, stream, la, cw, cb, locPad);
    hipLaunchKernelGGL(k_prep_add, dim3(kB * 4),        dim3(256), 0, stream, dec, W, bias, add);
    hipLaunchKernelGGL(k_main,     dim3((kM / 128) * 4), dim3(512), 0, stream, enc, Bf, locPad, add, wv, spart);
    hipLaunchKernelGGL(k_softmax,  dim3(kB),            dim3(256), 0, stream, spart, out_align);
    hipLaunchKernelGGL(k_ctx_part, dim3(8, kB),         dim3(256), 0, stream, enc, out_align, cpart);
    hipLaunchKernelGGL(k_ctx_red,  dim3(kB * kH / 256), dim3(256), 0, stream, cpart, out_ctx);
}

// Round 9
// 212.092 us; speedup vs baseline: 1.2931x; 1.0436x over previous
//
#include <hip/hip_runtime.h>
#include <hip/hip_bf16.h>
#include <hip/hip_fp16.h>

// Bahdanau location-sensitive attention, fused f16-MFMA implementation.
// R9: R8 shell (2 blocks/CU, simple 2-barrier loop, direct-enc support) with the
//     A-path fixed: write-side f32->f16 cvt (16 cvt/thread) into a f16 As (16 KB),
//     halving A LDS-read traffic and cutting loop VALU 4x. LDS 52 KB/block.
// B=32 T=1536 H=1024 CTX=1024 CONV_OUT=32

constexpr int kB = 32, kT = 1536, kH = 1024, kC = 1024, kCO = 32;
constexpr int kM = kB * kT;      // 49152
constexpr int kKb = 1088;        // padded B K: 1024 V | 32 U | 32 zero

typedef _Float16 f16;
typedef _Float16 f16x8 __attribute__((ext_vector_type(8)));
typedef float f32x4 __attribute__((ext_vector_type(4)));

// ---- ws layout (bytes) ----
constexpr size_t WS_B     = 0;                                   // kC*kKb f16  (2.2 MB)
constexpr size_t WS_LOC   = WS_B + (size_t)kC * kKb * 2;         // kM*64 f16   (6.3 MB)
constexpr size_t WS_ADD   = WS_LOC + (size_t)kM * 64 * 2;        // kB*kC f32
constexpr size_t WS_SCORE = WS_ADD + (size_t)kB * kC * 4;        // 4*kM f32
constexpr size_t WS_CTXP  = WS_SCORE + (size_t)4 * kM * 4;       // 8*kB*kH f32

__device__ __forceinline__ void gload16(const void* g, void* l) {
    __builtin_amdgcn_global_load_lds(
        (const __attribute__((address_space(1))) void*)g,
        (__attribute__((address_space(3))) void*)l, 16, 0, 0);
}

// ---------------------------------------------------------------- B pack [kC][1088] f16
__global__ void k_prep_b2(const float* __restrict__ V, const float* __restrict__ U,
                          f16* __restrict__ Bf) {
    int c = blockIdx.x;
    for (int k = threadIdx.x; k < kKb; k += 256) {
        float v = (k < kH) ? V[(size_t)c * kH + k]
                : (k < kH + kCO) ? U[(size_t)c * kCO + (k - kH)] : 0.f;
        Bf[(size_t)c * kKb + k] = (f16)v;
    }
}

// ---------------------------------------------------------------- conv1d -> locPad [M][64] f16 (cols 0..31)
__global__ void k_loc(const float* __restrict__ la, const float* __restrict__ cw,
                      const float* __restrict__ cb, f16* __restrict__ locPad) {
    int m = blockIdx.x * 256 + threadIdx.x;          // < kM
    int b = m / kT, t = m - b * kT;
    float x0 = (t > 0)      ? la[(size_t)b * kT + t - 1] : 0.f;
    float x1 = la[(size_t)b * kT + t];
    float x2 = (t < kT - 1) ? la[(size_t)b * kT + t + 1] : 0.f;
    union { f16 h[32]; int4 q[4]; } u;
#pragma unroll
    for (int k = 0; k < 32; ++k)
        u.h[k] = (f16)(cw[k * 3] * x0 + cw[k * 3 + 1] * x1 + cw[k * 3 + 2] * x2 + cb[k]);
    int4* dst = (int4*)(locPad + (size_t)m * 64);
    dst[0] = u.q[0]; dst[1] = u.q[1]; dst[2] = u.q[2]; dst[3] = u.q[3];
    // cols 32..63: staged to LDS in the tail but never ds_read
}

// ---------------------------------------------------------------- prep add = dec@W^T + bias
__global__ void k_prep_add(const float* __restrict__ dec, const float* __restrict__ W,
                           const float* __restrict__ bias, float* __restrict__ add) {
    __shared__ float dl[kH];
    int bb = blockIdx.x >> 2;
    int cc = (blockIdx.x & 3) * 256 + threadIdx.x;
    *(float4*)&dl[threadIdx.x * 4] = *(const float4*)&dec[(size_t)bb * kH + threadIdx.x * 4];
    __syncthreads();
    float acc = bias[cc];
    const float* wr = W + (size_t)cc * kH;
    for (int h = 0; h < kH; h += 4) {
        float4 wv = *(const float4*)&wr[h];
        acc += wv.x * dl[h] + wv.y * dl[h + 1] + wv.z * dl[h + 2] + wv.w * dl[h + 3];
    }
    add[(size_t)bb * kC + cc] = acc;
}

// ---------------------------------------------------------------- fused main GEMM
// Tile 128(M) x 256(N), BK=64, 512 thr = 8 waves (2M x 4N), per-wave 64x64.
// LDS (53248 B): As f16 [128 rows][8 chunks 16B, XOR row&7] @0 (16 KB);
//   Bs f16 [256 rows][8 chunks, XOR row&7] @16384 (32 KB); add_l @49152;
//   w_l @50176; sred @51200. Simple 2-barrier loop (m97 regime: compiler
//   schedules waits). 2 blocks/CU -> cross-block TLP hides stage drains.
__launch_bounds__(512, 4)
__global__ void k_main(const float* __restrict__ enc, const f16* __restrict__ Bf,
                       const f16* __restrict__ locPad, const float* __restrict__ add,
                       const float* __restrict__ wvec, float* __restrict__ spart) {
    __shared__ __align__(16) char smem[53248];
    float* add_l = (float*)(smem + 49152);
    float* w_l   = (float*)(smem + 50176);
    float (*sred)[64][4] = (float (*)[64][4])(smem + 51200);

    const int tid = threadIdx.x, lane = tid & 63, wave = tid >> 6;
    const int wm = wave >> 2, wn = wave & 3;
    // bijective XCD swizzle: 1536 blocks = 8 XCDs x 192; 4 consecutive share an A strip
    const int raw = blockIdx.x;
    const int lin = (raw & 7) * 192 + (raw >> 3);
    const int mt = lin >> 2, nt = lin & 3;
    const int m0 = mt * 128, n0 = nt * 256;
    const int bb = m0 / kT;                          // 128 | 1536

    if (tid < 256) {
        add_l[tid] = add[(size_t)bb * kC + n0 + tid];
        w_l[tid]   = wvec[n0 + tid];
    }

    f32x4 acc[4][4];
#pragma unroll
    for (int i = 0; i < 4; ++i)
#pragma unroll
        for (int j = 0; j < 4; ++j) acc[i][j] = (f32x4){0.f, 0.f, 0.f, 0.f};

    // A staging (write-side cvt): 4 thr/row, 16 f32 each -> 2 swizzled ds_write_b128
    const int ar = tid >> 2, aq = tid & 3;
    const float* aSrc = enc + (size_t)(m0 + ar) * kH + aq * 16;
    char* aw = smem + ar * 128;
    const int axm = ar & 7;

    // B staging (gload_lds): 4 instr/wave, each 8 rows x 128B; linear dest,
    // inverse-swizzled source chunk gcB = (lane&7) ^ (row&7).
    const int rB = lane >> 3;
    const int gcB = (lane & 7) ^ rB;
    const f16* bSrc[4];
#pragma unroll
    for (int j = 0; j < 4; ++j)
        bSrc[j] = Bf + (size_t)(n0 + wave * 32 + j * 8 + rB) * kKb + gcB * 8;
    const unsigned bDst = 16384u + wave * 4096u;

    const int g = lane >> 4, rl = lane & 15;

    for (int t = 0; t < 16; ++t) {
        // ---- stage: A f32 loads first (longest chain), B gloads, cvt+write
        const float* ap = aSrc + t * 64;
        float4 f0 = *(const float4*)(ap);
        float4 f1 = *(const float4*)(ap + 4);
        float4 f2 = *(const float4*)(ap + 8);
        float4 f3 = *(const float4*)(ap + 12);
#pragma unroll
        for (int j = 0; j < 4; ++j) gload16(bSrc[j] + t * 64, smem + bDst + j * 1024);
        union { f16 h[16]; int4 q[2]; } pk;
        pk.h[0] = (f16)f0.x;  pk.h[1] = (f16)f0.y;  pk.h[2] = (f16)f0.z;  pk.h[3] = (f16)f0.w;
        pk.h[4] = (f16)f1.x;  pk.h[5] = (f16)f1.y;  pk.h[6] = (f16)f1.z;  pk.h[7] = (f16)f1.w;
        pk.h[8] = (f16)f2.x;  pk.h[9] = (f16)f2.y;  pk.h[10] = (f16)f2.z; pk.h[11] = (f16)f2.w;
        pk.h[12] = (f16)f3.x; pk.h[13] = (f16)f3.y; pk.h[14] = (f16)f3.z; pk.h[15] = (f16)f3.w;
        *(int4*)(aw + (((aq * 2 + 0) ^ axm) * 16)) = pk.q[0];
        *(int4*)(aw + (((aq * 2 + 1) ^ axm) * 16)) = pk.q[1];
        __syncthreads();
        // ---- compute: 2 kk x 16 MFMA (compiler-scheduled lgkm)
#pragma unroll
        for (int kk = 0; kk < 2; ++kk) {
            f16x8 bfv[4], af[4];
#pragma unroll
            for (int ni = 0; ni < 4; ++ni)
                bfv[ni] = *(const f16x8*)(smem + 16384 + (wn * 64 + ni * 16 + rl) * 128
                                          + (((kk * 4 + g) ^ (rl & 7)) << 4));
#pragma unroll
            for (int mi = 0; mi < 4; ++mi)
                af[mi] = *(const f16x8*)(smem + (wm * 64 + mi * 16 + rl) * 128
                                         + (((kk * 4 + g) ^ (rl & 7)) << 4));
#pragma unroll
            for (int mi = 0; mi < 4; ++mi)
#pragma unroll
                for (int ni = 0; ni < 4; ++ni)
                    acc[mi][ni] = __builtin_amdgcn_mfma_f32_16x16x32_f16(af[mi], bfv[ni], acc[mi][ni], 0, 0, 0);
        }
        __syncthreads();
    }

    // ---- tail: loc @ U^T, K=32 (A rows from locPad f16; B cols 1024.. incl zero pad)
    {
        const f16* tS0 = locPad + (size_t)(m0 + wave * 16 + 0 + rB) * 64 + gcB * 8;
        const f16* tS1 = locPad + (size_t)(m0 + wave * 16 + 8 + rB) * 64 + gcB * 8;
        gload16(tS0, smem + wave * 2048u);
        gload16(tS1, smem + wave * 2048u + 1024u);
#pragma unroll
        for (int j = 0; j < 4; ++j) gload16(bSrc[j] + 1024, smem + bDst + j * 1024);
        __syncthreads();
        f16x8 bfv[4], af[4];
#pragma unroll
        for (int ni = 0; ni < 4; ++ni)
            bfv[ni] = *(const f16x8*)(smem + 16384 + (wn * 64 + ni * 16 + rl) * 128
                                      + ((g ^ (rl & 7)) << 4));
#pragma unroll
        for (int mi = 0; mi < 4; ++mi)
            af[mi] = *(const f16x8*)(smem + (wm * 64 + mi * 16 + rl) * 128
                                     + ((g ^ (rl & 7)) << 4));
#pragma unroll
        for (int mi = 0; mi < 4; ++mi)
#pragma unroll
            for (int ni = 0; ni < 4; ++ni)
                acc[mi][ni] = __builtin_amdgcn_mfma_f32_16x16x32_f16(af[mi], bfv[ni], acc[mi][ni], 0, 0, 0);
        __syncthreads();
    }

    // ---- epilogue: e = tanh(acc + add[c]); partial score = sum_c e*w[c]
#pragma unroll
    for (int mi = 0; mi < 4; ++mi) {
#pragma unroll
        for (int i = 0; i < 4; ++i) {
            float p = 0.f;
#pragma unroll
            for (int ni = 0; ni < 4; ++ni) {
                int cl = wn * 64 + ni * 16 + rl;
                float e = tanhf(acc[mi][ni][i] + add_l[cl]);
                p += e * w_l[cl];
            }
            p += __shfl_xor(p, 1);
            p += __shfl_xor(p, 2);
            p += __shfl_xor(p, 4);
            p += __shfl_xor(p, 8);
            if (rl == 0) sred[wm][mi * 16 + g * 4 + i][wn] = p;
        }
    }
    __syncthreads();
    if (tid < 128) {
        int r = tid & 63, w2 = tid >> 6;
        float s = sred[w2][r][0] + sred[w2][r][1] + sred[w2][r][2] + sred[w2][r][3];
        spart[(size_t)nt * kM + m0 + tid] = s;
    }
}

// ---------------------------------------------------------------- softmax over T
__global__ void k_softmax(const float* __restrict__ spart, float* __restrict__ out_align) {
    __shared__ float red[256];
    int b = blockIdx.x, tid = threadIdx.x;
    float v[6];
    float mx = -1e30f;
#pragma unroll
    for (int i = 0; i < 6; ++i) {
        size_t idx = (size_t)b * kT + tid + i * 256;
        float s = spart[idx] + spart[kM + idx] + spart[2 * (size_t)kM + idx] + spart[3 * (size_t)kM + idx];
        v[i] = s; mx = fmaxf(mx, s);
    }
    red[tid] = mx; __syncthreads();
    for (int o = 128; o > 0; o >>= 1) { if (tid < o) red[tid] = fmaxf(red[tid], red[tid + o]); __syncthreads(); }
    mx = red[0]; __syncthreads();
    float sum = 0.f;
#pragma unroll
    for (int i = 0; i < 6; ++i) { v[i] = expf(v[i] - mx); sum += v[i]; }
    red[tid] = sum; __syncthreads();
    for (int o = 128; o > 0; o >>= 1) { if (tid < o) red[tid] += red[tid + o]; __syncthreads(); }
    float inv = 1.f / red[0];
#pragma unroll
    for (int i = 0; i < 6; ++i)
        out_align[(size_t)b * kT + tid + i * 256] = v[i] * inv;
}

// ---------------------------------------------------------------- context
__global__ void k_ctx_part(const float* __restrict__ enc, const float* __restrict__ align,
                           float* __restrict__ cpart) {
    __shared__ float al[192];
    int ci = blockIdx.x, b = blockIdx.y, tid = threadIdx.x;
    if (tid < 192) al[tid] = align[(size_t)b * kT + ci * 192 + tid];
    __syncthreads();
    float4 acc = {0.f, 0.f, 0.f, 0.f};
    const float* ep = enc + ((size_t)b * kT + (size_t)ci * 192) * kH + tid * 4;
    for (int t = 0; t < 192; ++t) {
        float a = al[t];
        float4 e = *(const float4*)(ep + (size_t)t * kH);
        acc.x += a * e.x; acc.y += a * e.y; acc.z += a * e.z; acc.w += a * e.w;
    }
    *(float4*)&cpart[((size_t)ci * kB + b) * kH + tid * 4] = acc;
}

__global__ void k_ctx_red(const float* __restrict__ cpart, float* __restrict__ out_ctx) {
    int idx = blockIdx.x * 256 + threadIdx.x;
    float s = 0.f;
#pragma unroll
    for (int ci = 0; ci < 8; ++ci) s += cpart[(size_t)ci * kB * kH + idx];
    out_ctx[idx] = s;
}

// ---------------------------------------------------------------- launch
extern "C" void kernel_launch(void* const* d_in, const int* in_sizes, int n_in,
                              void* d_out, int out_size, void* d_ws, size_t ws_size,
                              hipStream_t stream) {
    const float* dec  = (const float*)d_in[0];
    const float* enc  = (const float*)d_in[1];
    const float* la   = (const float*)d_in[2];
    const float* W    = (const float*)d_in[3];
    const float* V    = (const float*)d_in[4];
    const float* U    = (const float*)d_in[5];
    const float* bias = (const float*)d_in[6];
    const float* wv   = (const float*)d_in[7];
    const float* cw   = (const float*)d_in[8];
    const float* cb   = (const float*)d_in[9];

    char* ws = (char*)d_ws;
    f16* Bf      = (f16*)(ws + WS_B);
    f16* locPad  = (f16*)(ws + WS_LOC);
    float* add   = (float*)(ws + WS_ADD);
    float* spart = (float*)(ws + WS_SCORE);
    float* cpart = (float*)(ws + WS_CTXP);

    float* out_ctx   = (float*)d_out;            // (B,H)
    float* out_align = (float*)d_out + kB * kH;  // (B,T)

    hipLaunchKernelGGL(k_prep_b2,  dim3(kC),            dim3(256), 0, stream, V, U, Bf);
    hipLaunchKernelGGL(k_loc,      dim3(kM / 256),      dim3(256), 0, stream, la, cw, cb, locPad);
    hipLaunchKernelGGL(k_prep_add, dim3(kB * 4),        dim3(256), 0, stream, dec, W, bias, add);
    hipLaunchKernelGGL(k_main,     dim3((kM / 128) * 4), dim3(512), 0, stream, enc, Bf, locPad, add, wv, spart);
    hipLaunchKernelGGL(k_softmax,  dim3(kB),            dim3(256), 0, stream, spart, out_align);
    hipLaunchKernelGGL(k_ctx_part, dim3(8, kB),         dim3(256), 0, stream, enc, out_align, cpart);
    hipLaunchKernelGGL(k_ctx_red,  dim3(kB * kH / 256), dim3(256), 0, stream, cpart, out_ctx);
}